// Round 20
// baseline (309.130 us; speedup 1.0000x reference)
//
#include <hip/hip_runtime.h>
#include <hip/hip_bf16.h>
#include <math.h>

// Problem constants
#define B_    32
#define IC    512
#define OC    256
#define HW    32
#define OHW   64

// ws layout (split path):
//   xcl at 0:         bf16 [32][34][34][512] = 37,879,808
//   A2  at 37879808:  bf16 [4][256][2048]    =  4,194,304
//   Y   at 42074112:  bf16 [4][32][34][34][256] = 75,890,688
#define WS_A2_OFF 37879808ull
#define WS_Y_OFF  42074112ull

typedef __attribute__((ext_vector_type(8))) short short8;
typedef __attribute__((ext_vector_type(4))) float f32x4;
typedef __attribute__((ext_vector_type(2))) float f32x2;

#define GPTR(x) ((const __attribute__((address_space(1))) char*)(x))
#define LPTR(x) ((__attribute__((address_space(3))) char*)(x))

// ---------------------------------------------------------------------------
// Fused prep: blocks 0..1087 = xprep (x fp32 NCHW -> xcl bf16 padded CL);
//             blocks 1088..1599 = wtrans2 (w -> A2 tap matrix).
__global__ __launch_bounds__(256) void prep(const float* __restrict__ x,
                                            const float* __restrict__ w,
                                            __hip_bfloat16* __restrict__ xcl,
                                            __hip_bfloat16* __restrict__ A2) {
    if (blockIdx.x < 1088) {
        int blk = blockIdx.x;
        int b = blk / 34, h = blk % 34;
        __hip_bfloat16* orow = xcl + (size_t)(b * 34 + h) * 34 * 512;
        int t = threadIdx.x;
        bool hin = (h >= 1 && h <= 32);

        for (int i = t; i < 2 * 512; i += 256) {
            int wsel = i >> 9, ic = i & 511;
            orow[(size_t)(wsel * 33) * 512 + ic] = __float2bfloat16(0.f);
        }

        __shared__ float ls[16][33];
        int icl_r = t >> 5, wv_r = t & 31;
        int wv_w = t >> 3, icl_w = t & 7;

        for (int ic0 = 0; ic0 < 512; ic0 += 16) {
            __syncthreads();
#pragma unroll
            for (int pp = 0; pp < 2; ++pp) {
                int icll = icl_r + pp * 8;
                float v = 0.f;
                if (hin) v = x[(((size_t)b * IC + ic0 + icll) * HW + (h - 1)) * HW + wv_r];
                ls[icll][wv_r] = v;
            }
            __syncthreads();
#pragma unroll
            for (int pp = 0; pp < 2; ++pp) {
                int icll = icl_w + pp * 8;
                orow[(size_t)(wv_w + 1) * 512 + ic0 + icll] = __float2bfloat16(ls[icll][wv_w]);
            }
        }
    } else {
        int t = (blockIdx.x - 1088) * 256 + threadIdx.x;   // 131072
        int ic = t & 511, oc = t >> 9;
        const float gain = 1.0f / sqrtf((float)(IC * 9));
        const float* wp = w + ((size_t)oc * IC + ic) * 9;
        float wl[3][3];
#pragma unroll
        for (int i = 0; i < 3; ++i)
#pragma unroll
            for (int j = 0; j < 3; ++j) wl[i][j] = wp[i * 3 + j] * gain;

        auto put = [&](int p, int kt, float v) {
            A2[((size_t)(p * 256 + oc) * 2048) + kt * 512 + ic] = __float2bfloat16(v);
        };
        put(0, 0, wl[0][0]); put(0, 1, wl[0][2]); put(0, 2, wl[2][0]); put(0, 3, wl[2][2]);
        put(1, 0, wl[0][1]); put(1, 1, wl[2][1]);
        put(2, 0, wl[1][0]); put(2, 1, wl[1][2]);
        put(3, 0, wl[1][1]);
    }
}

// ---------------------------------------------------------------------------
// Stage 1 (R20): A/B isolation — R18's EXACT measured-137µs work mapping
// (blocks 0..144: {p0 nt, p3 nt}; 145..212: three p1/p2; 213..255: two) +
// ONLY the scratch-fix from R19 (named-scalar tap addresses, uniform
// ternary select; unit derivation arithmetic per-j, no arrays).
// R19's XCD-slab mapping is REVERTED (implicated: slab B-panels 4.7 MB >
// 4 MB per-XCD L2 -> thrash; real FETCH 88->133 MB, stalls on vmcnt).
// Inner loop = R4-verified: 256x256, BK=32, 8 waves, ring-4, vmcnt(4),
// zero-conflict swizzle, setprio, 1 barrier/tile.
__global__ __launch_bounds__(512, 2) void gemm1(const __hip_bfloat16* __restrict__ A2,
                                                const __hip_bfloat16* __restrict__ xcl,
                                                __hip_bfloat16* __restrict__ Y) {
    __shared__ __align__(1024) char lds[4 * 32768];

    int blk = blockIdx.x;            // 0..255
    int tid = threadIdx.x;
    int wid = tid >> 6;
    int lane = tid & 63;
    int wr = wid >> 2;               // 0..1  (M half: oc wr*128..+127)
    int wc = wid & 3;                // 0..3  (N quarter)
    int q = lane >> 4;
    int lr = lane & 15;

    int rowS = tid >> 2;             // 0..127
    int slt = tid & 3;
    int sgl = slt ^ ((rowS >> 1) & 3);

    int dA0 = wid * 1024;            // + lane*16 by HW
    int dA1 = 8192 + wid * 1024;
    int dB0 = 16384 + wid * 1024;
    int dB1 = 24576 + wid * 1024;

    int qs = (q ^ ((lr >> 1) & 3)) << 4;
    int A0 = (wr * 128 + lr) * 64 + qs;           // + mi*1024 imm
    int B0 = 16384 + (wc * 64 + lr) * 64 + qs;    // + ni*1024 imm

    const char* GB = (const char*)xcl;

    for (int j = 0; j < 3; ++j) {
        // ---- unit (p, nt, NT): R18 mapping, derived arithmetically ----
        int p, nt, NT;
        if (blk < 145) {
            if (j >= 2) break;
            p = (j == 0) ? 0 : 3;
            nt = blk;
            NT = (j == 0) ? 64 : 16;
        } else {
            int i = (blk - 145) + 111 * j;
            if (i >= 290) break;
            p = (i < 145) ? 1 : 2;
            nt = (i < 145) ? i : (i - 145);
            NT = 32;
        }

        const char* GA = (const char*)A2 + (size_t)p * 256 * 4096;  // pitch 4096
        int offA0 = rowS * 4096 + sgl * 16;
        int offA1 = (rowS + 128) * 4096 + sgl * 16;

        // ---- named-scalar tap addresses per chunk (NO arrays -> no scratch)
        int bt00_0, bt01_0, bt10_0, bt11_0, bt00_1, bt01_1, bt10_1, bt11_1;
        {
            int n = nt * 256 + rowS;
            if (n > 36991) n = 36991;
            int bI = n / 1156, r_ = n - bI * 1156;
            int sy = r_ / 34, ty = r_ - sy * 34;
            int sy1 = sy - 1; if (sy1 < 0) sy1 = 0;
            int ty1 = ty - 1; if (ty1 < 0) ty1 = 0;
            int base = bI * 34;
            bt00_0 = ((base + sy) * 34 + ty) * 1024 + sgl * 16;
            bt01_0 = ((base + sy) * 34 + ty1) * 1024 + sgl * 16;
            bt10_0 = ((base + sy1) * 34 + ty) * 1024 + sgl * 16;
            bt11_0 = ((base + sy1) * 34 + ty1) * 1024 + sgl * 16;
        }
        {
            int n = nt * 256 + 128 + rowS;
            if (n > 36991) n = 36991;
            int bI = n / 1156, r_ = n - bI * 1156;
            int sy = r_ / 34, ty = r_ - sy * 34;
            int sy1 = sy - 1; if (sy1 < 0) sy1 = 0;
            int ty1 = ty - 1; if (ty1 < 0) ty1 = 0;
            int base = bI * 34;
            bt00_1 = ((base + sy) * 34 + ty) * 1024 + sgl * 16;
            bt01_1 = ((base + sy) * 34 + ty1) * 1024 + sgl * 16;
            bt10_1 = ((base + sy1) * 34 + ty) * 1024 + sgl * 16;
            bt11_1 = ((base + sy1) * 34 + ty1) * 1024 + sgl * 16;
        }

        f32x4 acc[8][4];
#pragma unroll
        for (int mi = 0; mi < 8; ++mi)
#pragma unroll
            for (int ni = 0; ni < 4; ++ni) acc[mi][ni] = (f32x4){0.f, 0.f, 0.f, 0.f};

        auto STAGE = [&](int ks, int bufi) {
            int tap = ks >> 4, icc = ks & 15;
            int di = (p == 0) ? (tap >> 1) : ((p == 1) ? tap : 0);
            int dj = (p == 0) ? (tap & 1) : ((p == 2) ? tap : 0);
            int ba0 = di ? (dj ? bt11_0 : bt10_0) : (dj ? bt01_0 : bt00_0);
            int ba1 = di ? (dj ? bt11_1 : bt10_1) : (dj ? bt01_1 : bt00_1);
            int ao = ks * 64;
            int ico = icc * 64;
            char* L = lds + bufi * 32768;
            __builtin_amdgcn_global_load_lds(GPTR(GA + offA0 + ao), LPTR(L + dA0), 16, 0, 0);
            __builtin_amdgcn_global_load_lds(GPTR(GA + offA1 + ao), LPTR(L + dA1), 16, 0, 0);
            __builtin_amdgcn_global_load_lds(GPTR(GB + ba0 + ico), LPTR(L + dB0), 16, 0, 0);
            __builtin_amdgcn_global_load_lds(GPTR(GB + ba1 + ico), LPTR(L + dB1), 16, 0, 0);
        };

        STAGE(0, 0);
        STAGE(1, 1);

        for (int t = 0; t < NT; ++t) {
            asm volatile("s_waitcnt vmcnt(4)" ::: "memory");   // tile t landed
            __builtin_amdgcn_s_barrier();
            __builtin_amdgcn_sched_barrier(0);

            STAGE(t + 2 < NT ? t + 2 : NT - 1, (t + 2) & 3);

            const char* Lc = lds + (t & 3) * 32768;
            short8 aF[8], bF[4];
#pragma unroll
            for (int mi = 0; mi < 8; ++mi) aF[mi] = *(const short8*)(Lc + A0 + mi * 1024);
#pragma unroll
            for (int ni = 0; ni < 4; ++ni) bF[ni] = *(const short8*)(Lc + B0 + ni * 1024);

            __builtin_amdgcn_s_setprio(1);
#pragma unroll
            for (int mi = 0; mi < 8; ++mi)
#pragma unroll
                for (int ni = 0; ni < 4; ++ni)
                    acc[mi][ni] = __builtin_amdgcn_mfma_f32_16x16x32_bf16(
                        aF[mi], bF[ni], acc[mi][ni], 0, 0, 0);
            __builtin_amdgcn_s_setprio(0);
        }
        asm volatile("s_waitcnt vmcnt(0)" ::: "memory");   // drain clamped stages

        // ---- epilogue: ushort4 per (mi,ni) ----
#pragma unroll
        for (int ni = 0; ni < 4; ++ni) {
            int n = nt * 256 + wc * 64 + ni * 16 + lr;
            if (n < 36992) {
                int bI = n / 1156, r2 = n - bI * 1156;
                int sy = r2 / 34, ty = r2 - sy * 34;
                size_t rowbase = ((size_t)((p * 32 + bI) * 34 + sy) * 34 + ty) * 256;
#pragma unroll
                for (int mi = 0; mi < 8; ++mi) {
                    int oc = wr * 128 + mi * 16 + (lane >> 4) * 4;
                    ushort4 st;
                    __hip_bfloat16 h0 = __float2bfloat16(acc[mi][ni][0]);
                    __hip_bfloat16 h1 = __float2bfloat16(acc[mi][ni][1]);
                    __hip_bfloat16 h2 = __float2bfloat16(acc[mi][ni][2]);
                    __hip_bfloat16 h3 = __float2bfloat16(acc[mi][ni][3]);
                    st.x = *reinterpret_cast<unsigned short*>(&h0);
                    st.y = *reinterpret_cast<unsigned short*>(&h1);
                    st.z = *reinterpret_cast<unsigned short*>(&h2);
                    st.w = *reinterpret_cast<unsigned short*>(&h3);
                    *reinterpret_cast<ushort4*>((char*)Y + (rowbase + oc) * 2) = st;
                }
            }
        }
    }
}

// ---------------------------------------------------------------------------
// Stage 2: depthwise FIR + bias + leaky*sqrt(2). Y is zero-padded (verified).
__global__ __launch_bounds__(256) void fir2(const __hip_bfloat16* __restrict__ Y,
                                            const float* __restrict__ bias,
                                            float* __restrict__ out) {
    int bid = blockIdx.x;            // 4096 = b(32) * u(32) * ocq(4)
    int b = bid >> 7, u = (bid >> 2) & 31, ocq = bid & 3;
    int tid = threadIdx.x;
    int oct = tid >> 5, v = tid & 31;
    int ocb = ocq * 64 + oct * 8;

    float o[2][2][8];
#pragma unroll
    for (int pm = 0; pm < 2; ++pm)
#pragma unroll
        for (int pn = 0; pn < 2; ++pn)
#pragma unroll
            for (int k = 0; k < 8; ++k) o[pm][pn][k] = 0.f;

    const int RE[2][2] = {{3, 1}, {1, 3}};
    const int RO[2][3] = {{1, 3, 0}, {0, 3, 1}};

#pragma unroll
    for (int aR = 0; aR < 2; ++aR) {
#pragma unroll
        for (int aC = 0; aC < 2; ++aC) {
            int p = aR * 2 + aC;
            int nR = aR ? 3 : 2, nC = aC ? 3 : 2;
            int syb = aR ? u : (u + 1);
            int tyb = aC ? v : (v + 1);
#pragma unroll
            for (int jr = 0; jr < 3; ++jr) {
                if (jr >= nR) continue;
#pragma unroll
                for (int jc = 0; jc < 3; ++jc) {
                    if (jc >= nC) continue;
                    size_t addr = ((size_t)((p * 32 + b) * 34 + syb + jr) * 34 +
                                   (tyb + jc)) * 256 + ocb;
                    short8 rv = *reinterpret_cast<const short8*>((const char*)Y + addr * 2);
                    float f[8];
#pragma unroll
                    for (int k = 0; k < 8; ++k)
                        f[k] = __uint_as_float(((unsigned)(unsigned short)rv[k]) << 16);
#pragma unroll
                    for (int pm = 0; pm < 2; ++pm) {
                        int rw = aR ? RO[pm][jr] : RE[pm][jr];
                        if (rw == 0) continue;
#pragma unroll
                        for (int pn = 0; pn < 2; ++pn) {
                            int cw = aC ? RO[pn][jc] : RE[pn][jc];
                            if (cw == 0) continue;
                            float wgt = (float)(rw * cw);
#pragma unroll
                            for (int k = 0; k < 8; ++k) o[pm][pn][k] += wgt * f[k];
                        }
                    }
                }
            }
        }
    }

    const float s2 = 1.41421356237309515f;
#pragma unroll
    for (int k = 0; k < 8; ++k) {
        float bv = bias[ocb + k];
#pragma unroll
        for (int pm = 0; pm < 2; ++pm) {
            float y0 = o[pm][0][k] * 0.0625f + bv;
            float y1 = o[pm][1][k] * 0.0625f + bv;
            y0 = (y0 >= 0.f ? y0 : 0.2f * y0) * s2;
            y1 = (y1 >= 0.f ? y1 : 0.2f * y1) * s2;
            size_t base = (((size_t)b * OC + ocb + k) * OHW + 2 * u + pm) * OHW + 2 * v;
            *(f32x2*)(out + base) = (f32x2){y0, y1};
        }
    }
}

// ---------------------------------------------------------------------------
extern "C" void kernel_launch(void* const* d_in, const int* in_sizes, int n_in,
                              void* d_out, int out_size, void* d_ws, size_t ws_size,
                              hipStream_t stream) {
    const float* x    = (const float*)d_in[0];
    const float* w    = (const float*)d_in[1];
    const float* bias = (const float*)d_in[2];
    float* out = (float*)d_out;

    __hip_bfloat16* xcl = (__hip_bfloat16*)d_ws;
    __hip_bfloat16* A2  = (__hip_bfloat16*)((char*)d_ws + WS_A2_OFF);
    __hip_bfloat16* Y   = (__hip_bfloat16*)((char*)d_ws + WS_Y_OFF);

    prep<<<1600, 256, 0, stream>>>(x, w, xcl, A2);
    gemm1<<<256, 512, 0, stream>>>(A2, xcl, Y);
    fir2<<<4096, 256, 0, stream>>>(Y, bias, out);
}

// Round 21
// 225.562 us; speedup vs baseline: 1.3705x; 1.3705x over previous
//
#include <hip/hip_runtime.h>
#include <hip/hip_bf16.h>
#include <math.h>

// Problem constants
#define B_    32
#define IC    512
#define OC    256
#define HW    32
#define OHW   64

// ws layout (split path):
//   xcl at 0:         bf16 [32][34][34][512] = 37,879,808
//   A2  at 37879808:  bf16 [4][256][2048]    =  4,194,304
//   Y   at 42074112:  bf16 [4][32][34][34][256] = 75,890,688
#define WS_A2_OFF 37879808ull
#define WS_Y_OFF  42074112ull

typedef __attribute__((ext_vector_type(8))) short short8;
typedef __attribute__((ext_vector_type(4))) float f32x4;
typedef __attribute__((ext_vector_type(2))) float f32x2;

#define GPTR(x) ((const __attribute__((address_space(1))) char*)(x))
#define LPTR(x) ((__attribute__((address_space(3))) char*)(x))

// ---------------------------------------------------------------------------
// Fused prep: blocks 0..1087 = xprep (x fp32 NCHW -> xcl bf16 padded CL);
//             blocks 1088..1599 = wtrans2 (w -> A2 tap matrix).
__global__ __launch_bounds__(256) void prep(const float* __restrict__ x,
                                            const float* __restrict__ w,
                                            __hip_bfloat16* __restrict__ xcl,
                                            __hip_bfloat16* __restrict__ A2) {
    if (blockIdx.x < 1088) {
        int blk = blockIdx.x;
        int b = blk / 34, h = blk % 34;
        __hip_bfloat16* orow = xcl + (size_t)(b * 34 + h) * 34 * 512;
        int t = threadIdx.x;
        bool hin = (h >= 1 && h <= 32);

        for (int i = t; i < 2 * 512; i += 256) {
            int wsel = i >> 9, ic = i & 511;
            orow[(size_t)(wsel * 33) * 512 + ic] = __float2bfloat16(0.f);
        }

        __shared__ float ls[16][33];
        int icl_r = t >> 5, wv_r = t & 31;
        int wv_w = t >> 3, icl_w = t & 7;

        for (int ic0 = 0; ic0 < 512; ic0 += 16) {
            __syncthreads();
#pragma unroll
            for (int pp = 0; pp < 2; ++pp) {
                int icll = icl_r + pp * 8;
                float v = 0.f;
                if (hin) v = x[(((size_t)b * IC + ic0 + icll) * HW + (h - 1)) * HW + wv_r];
                ls[icll][wv_r] = v;
            }
            __syncthreads();
#pragma unroll
            for (int pp = 0; pp < 2; ++pp) {
                int icll = icl_w + pp * 8;
                orow[(size_t)(wv_w + 1) * 512 + ic0 + icll] = __float2bfloat16(ls[icll][wv_w]);
            }
        }
    } else {
        int t = (blockIdx.x - 1088) * 256 + threadIdx.x;   // 131072
        int ic = t & 511, oc = t >> 9;
        const float gain = 1.0f / sqrtf((float)(IC * 9));
        const float* wp = w + ((size_t)oc * IC + ic) * 9;
        float wl[3][3];
#pragma unroll
        for (int i = 0; i < 3; ++i)
#pragma unroll
            for (int j = 0; j < 3; ++j) wl[i][j] = wp[i * 3 + j] * gain;

        auto put = [&](int p, int kt, float v) {
            A2[((size_t)(p * 256 + oc) * 2048) + kt * 512 + ic] = __float2bfloat16(v);
        };
        put(0, 0, wl[0][0]); put(0, 1, wl[0][2]); put(0, 2, wl[2][0]); put(0, 3, wl[2][2]);
        put(1, 0, wl[0][1]); put(1, 1, wl[2][1]);
        put(2, 0, wl[1][0]); put(2, 1, wl[1][2]);
        put(3, 0, wl[1][1]);
    }
}

// ---------------------------------------------------------------------------
// Stage 1 (R21 = R18 VERBATIM, the measured-137µs configuration).
// Persistent static-balanced schedule, 256 blocks (1/CU). R20's A/B proved
// the "scratch-free" rewrite REGRESSED (+56 MB real spill traffic, 137->220):
// the small hot bt[2][2][2] scratch array is L1-resident and nearly free,
// while 8 extra live scalars across the 128-reg acc loop forced spills.
// Keep the scratch arrays. Inner loop = R4-verified: 256x256, BK=32,
// 8 waves, ring-4, vmcnt(4), zero-conflict swizzle, setprio, 1 barrier/tile.
__global__ __launch_bounds__(512, 2) void gemm1(const __hip_bfloat16* __restrict__ A2,
                                                const __hip_bfloat16* __restrict__ xcl,
                                                __hip_bfloat16* __restrict__ Y) {
    __shared__ __align__(1024) char lds[4 * 32768];

    int blk = blockIdx.x;            // 0..255
    int tid = threadIdx.x;
    int wid = tid >> 6;
    int lane = tid & 63;
    int wr = wid >> 2;               // 0..1  (M half: oc wr*128..+127)
    int wc = wid & 3;                // 0..3  (N quarter)
    int q = lane >> 4;
    int lr = lane & 15;

    int rowS = tid >> 2;             // 0..127
    int slt = tid & 3;
    int sgl = slt ^ ((rowS >> 1) & 3);

    int dA0 = wid * 1024;            // + lane*16 by HW
    int dA1 = 8192 + wid * 1024;
    int dB0 = 16384 + wid * 1024;
    int dB1 = 24576 + wid * 1024;

    int qs = (q ^ ((lr >> 1) & 3)) << 4;
    int A0 = (wr * 128 + lr) * 64 + qs;           // + mi*1024 imm
    int B0 = 16384 + (wc * 64 + lr) * 64 + qs;    // + ni*1024 imm

    // ---- static unit list (R18 exact) ----
    int nu, ups[3], unts[3], uNTs[3];
    if (blk < 145) {
        nu = 2;
        ups[0] = 0; unts[0] = blk; uNTs[0] = 64;
        ups[1] = 3; unts[1] = blk; uNTs[1] = 16;
    } else {
        int qb = blk - 145;
        nu = 0;
#pragma unroll
        for (int j = 0; j < 3; ++j) {
            int i = qb + 111 * j;
            if (i < 290) {
                ups[nu] = (i < 145) ? 1 : 2;
                unts[nu] = (i < 145) ? i : (i - 145);
                uNTs[nu] = 32;
                ++nu;
            }
        }
    }

    const char* GB = (const char*)xcl;

    for (int uu = 0; uu < nu; ++uu) {
        int p = ups[uu], nt = unts[uu], NT = uNTs[uu];

        const char* GA = (const char*)A2 + (size_t)p * 256 * 4096;  // pitch 4096
        int offA0 = rowS * 4096 + sgl * 16;
        int offA1 = (rowS + 128) * 4096 + sgl * 16;

        int bt[2][2][2];             // [chunk][di][dj] tap base addresses
#pragma unroll
        for (int i = 0; i < 2; ++i) {
            int n = nt * 256 + i * 128 + rowS;
            if (n > 36991) n = 36991;
            int bI = n / 1156, r_ = n - bI * 1156;
            int sy = r_ / 34, ty = r_ - sy * 34;
#pragma unroll
            for (int di = 0; di < 2; ++di)
#pragma unroll
                for (int dj = 0; dj < 2; ++dj) {
                    int rr = sy - di; if (rr < 0) rr = 0;
                    int cc = ty - dj; if (cc < 0) cc = 0;
                    bt[i][di][dj] = ((bI * 34 + rr) * 34 + cc) * 1024 + sgl * 16;
                }
        }

        f32x4 acc[8][4];
#pragma unroll
        for (int mi = 0; mi < 8; ++mi)
#pragma unroll
            for (int ni = 0; ni < 4; ++ni) acc[mi][ni] = (f32x4){0.f, 0.f, 0.f, 0.f};

        auto STAGE = [&](int ks, int bufi) {
            int tap = ks >> 4, icc = ks & 15;
            int di, dj;
            if (p == 0) { di = tap >> 1; dj = tap & 1; }
            else if (p == 1) { di = tap; dj = 0; }
            else if (p == 2) { di = 0; dj = tap; }
            else { di = 0; dj = 0; }
            int ao = ks * 64;
            int ico = icc * 64;
            char* L = lds + bufi * 32768;
            __builtin_amdgcn_global_load_lds(GPTR(GA + offA0 + ao), LPTR(L + dA0), 16, 0, 0);
            __builtin_amdgcn_global_load_lds(GPTR(GA + offA1 + ao), LPTR(L + dA1), 16, 0, 0);
            __builtin_amdgcn_global_load_lds(GPTR(GB + bt[0][di][dj] + ico), LPTR(L + dB0), 16, 0, 0);
            __builtin_amdgcn_global_load_lds(GPTR(GB + bt[1][di][dj] + ico), LPTR(L + dB1), 16, 0, 0);
        };

        STAGE(0, 0);
        STAGE(1, 1);

        for (int t = 0; t < NT; ++t) {
            asm volatile("s_waitcnt vmcnt(4)" ::: "memory");   // tile t landed
            __builtin_amdgcn_s_barrier();
            __builtin_amdgcn_sched_barrier(0);

            STAGE(t + 2 < NT ? t + 2 : NT - 1, (t + 2) & 3);

            const char* Lc = lds + (t & 3) * 32768;
            short8 aF[8], bF[4];
#pragma unroll
            for (int mi = 0; mi < 8; ++mi) aF[mi] = *(const short8*)(Lc + A0 + mi * 1024);
#pragma unroll
            for (int ni = 0; ni < 4; ++ni) bF[ni] = *(const short8*)(Lc + B0 + ni * 1024);

            __builtin_amdgcn_s_setprio(1);
#pragma unroll
            for (int mi = 0; mi < 8; ++mi)
#pragma unroll
                for (int ni = 0; ni < 4; ++ni)
                    acc[mi][ni] = __builtin_amdgcn_mfma_f32_16x16x32_bf16(
                        aF[mi], bF[ni], acc[mi][ni], 0, 0, 0);
            __builtin_amdgcn_s_setprio(0);
        }
        asm volatile("s_waitcnt vmcnt(0)" ::: "memory");   // drain clamped stages

        // ---- epilogue: ushort4 per (mi,ni) ----
#pragma unroll
        for (int ni = 0; ni < 4; ++ni) {
            int n = nt * 256 + wc * 64 + ni * 16 + lr;
            if (n < 36992) {
                int bI = n / 1156, r2 = n - bI * 1156;
                int sy = r2 / 34, ty = r2 - sy * 34;
                size_t rowbase = ((size_t)((p * 32 + bI) * 34 + sy) * 34 + ty) * 256;
#pragma unroll
                for (int mi = 0; mi < 8; ++mi) {
                    int oc = wr * 128 + mi * 16 + (lane >> 4) * 4;
                    ushort4 st;
                    __hip_bfloat16 h0 = __float2bfloat16(acc[mi][ni][0]);
                    __hip_bfloat16 h1 = __float2bfloat16(acc[mi][ni][1]);
                    __hip_bfloat16 h2 = __float2bfloat16(acc[mi][ni][2]);
                    __hip_bfloat16 h3 = __float2bfloat16(acc[mi][ni][3]);
                    st.x = *reinterpret_cast<unsigned short*>(&h0);
                    st.y = *reinterpret_cast<unsigned short*>(&h1);
                    st.z = *reinterpret_cast<unsigned short*>(&h2);
                    st.w = *reinterpret_cast<unsigned short*>(&h3);
                    *reinterpret_cast<ushort4*>((char*)Y + (rowbase + oc) * 2) = st;
                }
            }
        }
    }
}

// ---------------------------------------------------------------------------
// Stage 2: depthwise FIR + bias + leaky*sqrt(2). Y is zero-padded (verified).
__global__ __launch_bounds__(256) void fir2(const __hip_bfloat16* __restrict__ Y,
                                            const float* __restrict__ bias,
                                            float* __restrict__ out) {
    int bid = blockIdx.x;            // 4096 = b(32) * u(32) * ocq(4)
    int b = bid >> 7, u = (bid >> 2) & 31, ocq = bid & 3;
    int tid = threadIdx.x;
    int oct = tid >> 5, v = tid & 31;
    int ocb = ocq * 64 + oct * 8;

    float o[2][2][8];
#pragma unroll
    for (int pm = 0; pm < 2; ++pm)
#pragma unroll
        for (int pn = 0; pn < 2; ++pn)
#pragma unroll
            for (int k = 0; k < 8; ++k) o[pm][pn][k] = 0.f;

    const int RE[2][2] = {{3, 1}, {1, 3}};
    const int RO[2][3] = {{1, 3, 0}, {0, 3, 1}};

#pragma unroll
    for (int aR = 0; aR < 2; ++aR) {
#pragma unroll
        for (int aC = 0; aC < 2; ++aC) {
            int p = aR * 2 + aC;
            int nR = aR ? 3 : 2, nC = aC ? 3 : 2;
            int syb = aR ? u : (u + 1);
            int tyb = aC ? v : (v + 1);
#pragma unroll
            for (int jr = 0; jr < 3; ++jr) {
                if (jr >= nR) continue;
#pragma unroll
                for (int jc = 0; jc < 3; ++jc) {
                    if (jc >= nC) continue;
                    size_t addr = ((size_t)((p * 32 + b) * 34 + syb + jr) * 34 +
                                   (tyb + jc)) * 256 + ocb;
                    short8 rv = *reinterpret_cast<const short8*>((const char*)Y + addr * 2);
                    float f[8];
#pragma unroll
                    for (int k = 0; k < 8; ++k)
                        f[k] = __uint_as_float(((unsigned)(unsigned short)rv[k]) << 16);
#pragma unroll
                    for (int pm = 0; pm < 2; ++pm) {
                        int rw = aR ? RO[pm][jr] : RE[pm][jr];
                        if (rw == 0) continue;
#pragma unroll
                        for (int pn = 0; pn < 2; ++pn) {
                            int cw = aC ? RO[pn][jc] : RE[pn][jc];
                            if (cw == 0) continue;
                            float wgt = (float)(rw * cw);
#pragma unroll
                            for (int k = 0; k < 8; ++k) o[pm][pn][k] += wgt * f[k];
                        }
                    }
                }
            }
        }
    }

    const float s2 = 1.41421356237309515f;
#pragma unroll
    for (int k = 0; k < 8; ++k) {
        float bv = bias[ocb + k];
#pragma unroll
        for (int pm = 0; pm < 2; ++pm) {
            float y0 = o[pm][0][k] * 0.0625f + bv;
            float y1 = o[pm][1][k] * 0.0625f + bv;
            y0 = (y0 >= 0.f ? y0 : 0.2f * y0) * s2;
            y1 = (y1 >= 0.f ? y1 : 0.2f * y1) * s2;
            size_t base = (((size_t)b * OC + ocb + k) * OHW + 2 * u + pm) * OHW + 2 * v;
            *(f32x2*)(out + base) = (f32x2){y0, y1};
        }
    }
}

// ---------------------------------------------------------------------------
extern "C" void kernel_launch(void* const* d_in, const int* in_sizes, int n_in,
                              void* d_out, int out_size, void* d_ws, size_t ws_size,
                              hipStream_t stream) {
    const float* x    = (const float*)d_in[0];
    const float* w    = (const float*)d_in[1];
    const float* bias = (const float*)d_in[2];
    float* out = (float*)d_out;

    __hip_bfloat16* xcl = (__hip_bfloat16*)d_ws;
    __hip_bfloat16* A2  = (__hip_bfloat16*)((char*)d_ws + WS_A2_OFF);
    __hip_bfloat16* Y   = (__hip_bfloat16*)((char*)d_ws + WS_Y_OFF);

    prep<<<1600, 256, 0, stream>>>(x, w, xcl, A2);
    gemm1<<<256, 512, 0, stream>>>(A2, xcl, Y);
    fir2<<<4096, 256, 0, stream>>>(Y, bias, out);
}